// Round 11
// baseline (702.964 us; speedup 1.0000x reference)
//
#include <hip/hip_runtime.h>
#include <hip/hip_fp16.h>

// GCN: 4x GCNConv(relu) -> global_add_pool -> MLP(96->32 relu ->1)
// N=100000 nodes, E=1600000 edges, F=32, H=96, G=2048 graphs.
//
// R11: (a) GEMMs moved to v_mfma_f32_16x16x32_f16 (were 50%-of-vector-peak
// fp32 VALU). W transposed to fp16 in LDS, +8 half padded stride (kills 8-way
// ds_read_b128 bank conflict). (b) aggregate: nontemporal col/val loads +
// nontemporal output store to reduce L2 pollution vs the gather operand.
// Aggregate structure per R10 (TPN=24 x uint2, pad4 rows, 4-way unroll) —
// measured floor across 7 structural variants.

#define HIDDEN 96

typedef __attribute__((ext_vector_type(8))) _Float16 half8;
typedef __attribute__((ext_vector_type(4))) float floatx4;
typedef __attribute__((ext_vector_type(4))) int iv4;
typedef __attribute__((ext_vector_type(4))) float fv4;
typedef __attribute__((ext_vector_type(2))) unsigned uv2;

__device__ inline float4 h4_to_f4(uint2 u) {
    __half2 a = *reinterpret_cast<__half2*>(&u.x);
    __half2 b = *reinterpret_cast<__half2*>(&u.y);
    float2 fa = __half22float2(a), fb = __half22float2(b);
    return make_float4(fa.x, fa.y, fb.x, fb.y);
}

__device__ inline uint2 f4_to_h4(float4 v) {
    __half2 a = __float22half2_rn(make_float2(v.x, v.y));
    __half2 b = __float22half2_rn(make_float2(v.z, v.w));
    uint2 u;
    u.x = *reinterpret_cast<unsigned*>(&a);
    u.y = *reinterpret_cast<unsigned*>(&b);
    return u;
}

__device__ inline int pad4i(int c) { return (c + 3) & ~3; }

__global__ __launch_bounds__(256) void zero_int_kernel(int* p, int n) {
    int i = blockIdx.x * 256 + threadIdx.x;
    if (i < n) p[i] = 0;
}

__global__ __launch_bounds__(256) void zero_kernel(float* p, int n) {
    int i = blockIdx.x * 256 + threadIdx.x;
    if (i < n) p[i] = 0.0f;
}

__global__ __launch_bounds__(256) void cast_h_kernel(const float4* __restrict__ in,
                                                     uint2* __restrict__ out, int n4) {
    int i = blockIdx.x * 256 + threadIdx.x;
    if (i < n4) out[i] = f4_to_h4(in[i]);
}

// in-degree histogram over dst; epos[e] = this edge's slot within its dst row
__global__ __launch_bounds__(256) void deg_pos_kernel(const int* __restrict__ dst,
                                                      int* __restrict__ cnt,
                                                      int* __restrict__ epos, int E) {
    int e = blockIdx.x * 256 + threadIdx.x;
    if (e < E) epos[e] = atomicAdd(&cnt[dst[e]], 1);
}

__global__ __launch_bounds__(256) void dinv_kernel(const int* __restrict__ cnt,
                                                   float* __restrict__ dinv, int n) {
    int i = blockIdx.x * 256 + threadIdx.x;
    if (i < n) dinv[i] = rsqrtf((float)(cnt[i] + 1));
}

// ---- 3-phase multi-block exclusive scan of pad4(cnt[0..N)) -> rowptr ----
__global__ __launch_bounds__(256) void scan_reduce_kernel(const int* __restrict__ cnt,
                                                          int* __restrict__ bsum, int N) {
    __shared__ int s[256];
    int b = blockIdx.x, tid = threadIdx.x;
    int base = b * 1024;
    int v = 0;
    for (int j = tid; j < 1024; j += 256) {
        int i = base + j;
        v += (i < N) ? pad4i(cnt[i]) : 0;
    }
    s[tid] = v;
    __syncthreads();
    for (int off = 128; off > 0; off >>= 1) {
        if (tid < off) s[tid] += s[tid + off];
        __syncthreads();
    }
    if (tid == 0) bsum[b] = s[0];
}

__global__ __launch_bounds__(128) void scan_bsum_kernel(int* __restrict__ bsum, int nb) {
    __shared__ int s[128];
    int tid = threadIdx.x;
    int v = (tid < nb) ? bsum[tid] : 0;
    s[tid] = v;
    __syncthreads();
    for (int off = 1; off < 128; off <<= 1) {
        int t = (tid >= off) ? s[tid - off] : 0;
        __syncthreads();
        s[tid] += t;
        __syncthreads();
    }
    if (tid < nb) bsum[tid] = s[tid] - v;  // exclusive
}

__global__ __launch_bounds__(256) void scan_write_kernel(const int* __restrict__ cnt,
                                                         const int* __restrict__ bsum,
                                                         int* __restrict__ rowptr, int N) {
    __shared__ int ts[256];
    int b = blockIdx.x, tid = threadIdx.x;
    int base = b * 1024 + tid * 4;
    int v0 = (base + 0 < N) ? pad4i(cnt[base + 0]) : 0;
    int v1 = (base + 1 < N) ? pad4i(cnt[base + 1]) : 0;
    int v2 = (base + 2 < N) ? pad4i(cnt[base + 2]) : 0;
    int v3 = (base + 3 < N) ? pad4i(cnt[base + 3]) : 0;
    int sum = v0 + v1 + v2 + v3;
    ts[tid] = sum;
    __syncthreads();
    for (int off = 1; off < 256; off <<= 1) {
        int t = (tid >= off) ? ts[tid - off] : 0;
        __syncthreads();
        ts[tid] += t;
        __syncthreads();
    }
    int excl = bsum[b] + ts[tid] - sum;
    if (base + 0 <= N) rowptr[base + 0] = excl;
    if (base + 1 <= N) rowptr[base + 1] = excl + v0;
    if (base + 2 <= N) rowptr[base + 2] = excl + v0 + v1;
    if (base + 3 <= N) rowptr[base + 3] = excl + v0 + v1 + v2;
}

// Fill CSR slots (no atomics). Padding slots stay col=0,val=0 (pre-zeroed).
__global__ __launch_bounds__(256) void fill_csr_kernel(const int* __restrict__ src,
                                                       const int* __restrict__ dst,
                                                       const int* __restrict__ epos,
                                                       const float* __restrict__ dinv,
                                                       const int* __restrict__ rowptr,
                                                       int* __restrict__ col,
                                                       float* __restrict__ val, int E) {
    int e = blockIdx.x * 256 + threadIdx.x;
    if (e >= E) return;
    int s = src[e];
    int d = dst[e];
    int idx = rowptr[d] + epos[e];
    col[idx] = s;
    val[idx] = dinv[s] * dinv[d];
}

// MFMA GEMM: Y[n x 96] (fp16) = act(X[n x K] fp16) @ W[K x 96] (+ b).
// v_mfma_f32_16x16x32_f16. Block = 4 waves; wave computes 16 rows x 96 cols
// (6 col-tiles x K/32 k-steps). W staged transposed in LDS as fp16, stride
// K+8 halfs (2-way-max bank aliasing on ds_read_b128).
// Fragments: A[m=lane&15][k=quad*8+j]; B[k=quad*8+j][ncol=lane&15];
// C/D: col=lane&15, row=quad*4+reg.
template <int K, bool RELU, bool BIAS>
__global__ __launch_bounds__(256) void gemm_mfma_kernel(const _Float16* __restrict__ X,
                                                        const float* __restrict__ W,
                                                        const float* __restrict__ b,
                                                        _Float16* __restrict__ Y, int n) {
    constexpr int KS = K + 8;
    __shared__ _Float16 blds[96 * KS];
    int tid = threadIdx.x;
    for (int idx = tid; idx < 96 * K; idx += 256) {
        int nn = idx / K, kk = idx - nn * K;
        blds[nn * KS + kk] = (_Float16)W[kk * 96 + nn];
    }
    __syncthreads();

    int wave = tid >> 6, lane = tid & 63;
    int m = lane & 15, quad = lane >> 4;
    int row0 = blockIdx.x * 64 + wave * 16;
    int rowA = row0 + m;                       // row this lane's A-frag feeds
    int rowc = (rowA < n) ? rowA : (n - 1);    // clamp (invalid rows unused)

    floatx4 acc[6];
#pragma unroll
    for (int t = 0; t < 6; t++) acc[t] = (floatx4){0.f, 0.f, 0.f, 0.f};

    const _Float16* xrow = X + (size_t)rowc * K;
#pragma unroll
    for (int k0 = 0; k0 < K; k0 += 32) {
        half8 a = *reinterpret_cast<const half8*>(xrow + k0 + quad * 8);
        if (RELU) {
#pragma unroll
            for (int j = 0; j < 8; j++) a[j] = (a[j] > (_Float16)0) ? a[j] : (_Float16)0;
        }
#pragma unroll
        for (int t = 0; t < 6; t++) {
            half8 bf = *reinterpret_cast<const half8*>(
                blds + (t * 16 + m) * KS + k0 + quad * 8);
            acc[t] = __builtin_amdgcn_mfma_f32_16x16x32_f16(a, bf, acc[t], 0, 0, 0);
        }
    }

#pragma unroll
    for (int t = 0; t < 6; t++) {
        float bb = BIAS ? b[t * 16 + m] : 0.f;
#pragma unroll
        for (int r = 0; r < 4; r++) {
            int rowO = row0 + quad * 4 + r;
            if (rowO < n) Y[(size_t)rowO * 96 + t * 16 + m] = (_Float16)(acc[t][r] + bb);
        }
    }
}

// out[i] = dinv[i]^2*xw[i] (+ b) + sum_e val[e]*xw[col[e]], xw fp16.
// TPN threads/node (uint2 8B lanes), pad4 rows, 4-way unroll.
// col/val loaded nontemporal; output stored nontemporal (L2 pollution control:
// keep the gather operand resident in the 4MiB per-XCD L2).
template <int TPN, bool POOL, bool BIAS>
__global__ __launch_bounds__(256) void aggregate_kernel(const uint2* __restrict__ xwh,
                                                        const int* __restrict__ rowptr,
                                                        const int* __restrict__ col,
                                                        const float* __restrict__ val,
                                                        const float* __restrict__ dinv,
                                                        const float* __restrict__ b,
                                                        uint2* __restrict__ out,
                                                        const int* __restrict__ batch,
                                                        float* __restrict__ gpool, int n) {
    unsigned t = blockIdx.x * 256 + threadIdx.x;
    unsigned i = t / (unsigned)TPN, q = t % (unsigned)TPN;
    if (i >= (unsigned)n) return;

    float dv = dinv[i];
    float s = dv * dv;
    float4 self = h4_to_f4(xwh[i * TPN + q]);
    float4 acc = make_float4(s * self.x, s * self.y, s * self.z, s * self.w);
    if (BIAS) {
        float4 bb = reinterpret_cast<const float4*>(b)[q];
        acc.x += bb.x; acc.y += bb.y; acc.z += bb.z; acc.w += bb.w;
    }

    int e = rowptr[i], end = rowptr[i + 1];
    for (; e < end; e += 4) {
        iv4 c4 = __builtin_nontemporal_load(reinterpret_cast<const iv4*>(col + e));
        fv4 w4 = __builtin_nontemporal_load(reinterpret_cast<const fv4*>(val + e));
        uint2 u0 = xwh[(unsigned)c4.x * TPN + q];
        uint2 u1 = xwh[(unsigned)c4.y * TPN + q];
        uint2 u2 = xwh[(unsigned)c4.z * TPN + q];
        uint2 u3 = xwh[(unsigned)c4.w * TPN + q];
        float4 v0 = h4_to_f4(u0), v1 = h4_to_f4(u1);
        float4 v2 = h4_to_f4(u2), v3 = h4_to_f4(u3);
        acc.x += w4.x * v0.x + w4.y * v1.x + w4.z * v2.x + w4.w * v3.x;
        acc.y += w4.x * v0.y + w4.y * v1.y + w4.z * v2.y + w4.w * v3.y;
        acc.z += w4.x * v0.z + w4.y * v1.z + w4.z * v2.z + w4.w * v3.z;
        acc.w += w4.x * v0.w + w4.y * v1.w + w4.z * v2.w + w4.w * v3.w;
    }

    if (POOL) {
        float* o = gpool + (size_t)batch[i] * (TPN * 4);
        unsigned fo = q * 4u;
        atomicAdd(o + fo + 0, fmaxf(acc.x, 0.f));
        atomicAdd(o + fo + 1, fmaxf(acc.y, 0.f));
        atomicAdd(o + fo + 2, fmaxf(acc.z, 0.f));
        atomicAdd(o + fo + 3, fmaxf(acc.w, 0.f));
    } else {
        uint2 h = f4_to_h4(acc);
        uv2 hv; hv.x = h.x; hv.y = h.y;
        __builtin_nontemporal_store(hv, reinterpret_cast<uv2*>(out + i * TPN + q));
    }
}

__global__ __launch_bounds__(64) void mlp_kernel(const float* __restrict__ g,
                                                 const float* __restrict__ Wf1,
                                                 const float* __restrict__ bf1,
                                                 const float* __restrict__ Wf2,
                                                 const float* __restrict__ bf2,
                                                 float* __restrict__ out, int G) {
    __shared__ float gs[HIDDEN];
    __shared__ float hid[32];
    int blk = blockIdx.x;
    int lane = threadIdx.x;
    for (int idx = lane; idx < HIDDEN; idx += 64) gs[idx] = g[(size_t)blk * HIDDEN + idx];
    __syncthreads();
    if (lane < 32) {
        float a = bf1[lane];
        for (int k = 0; k < HIDDEN; k++) a = fmaf(gs[k], Wf1[k * 32 + lane], a);
        hid[lane] = fmaxf(a, 0.f);
    }
    __syncthreads();
    if (lane == 0) {
        float o = bf2[0];
        for (int k = 0; k < 32; k++) o = fmaf(hid[k], Wf2[k], o);
        out[blk] = o;
    }
}

extern "C" void kernel_launch(void* const* d_in, const int* in_sizes, int n_in,
                              void* d_out, int out_size, void* d_ws, size_t ws_size,
                              hipStream_t stream) {
    const float* x     = (const float*)d_in[0];
    const int*   ei    = (const int*)d_in[1];
    const int*   batch = (const int*)d_in[2];
    const float* W1 = (const float*)d_in[3];  const float* b1 = (const float*)d_in[4];
    const float* W2 = (const float*)d_in[5];  const float* b2 = (const float*)d_in[6];
    const float* W3 = (const float*)d_in[7];  const float* b3 = (const float*)d_in[8];
    const float* W4 = (const float*)d_in[9];  const float* b4 = (const float*)d_in[10];
    const float* Wf1 = (const float*)d_in[11]; const float* bf1 = (const float*)d_in[12];
    const float* Wf2 = (const float*)d_in[13]; const float* bf2 = (const float*)d_in[14];
    float* out = (float*)d_out;

    int N = in_sizes[0] / 32;   // 100000
    int E = in_sizes[1] / 2;    // 1600000
    int G = out_size;           // 2048
    const int* src = ei;
    const int* dst = ei + E;
    int Emax = E + 4 * N;       // pad4-CSR upper bound (2.0M)

    // Workspace layout (~72 MB)
    char* ws = (char*)d_ws;
    size_t off = 0;
    auto alloc = [&](size_t bytes) -> void* {
        void* p = (void*)(ws + off);
        off += (bytes + 255) & ~(size_t)255;
        return p;
    };
    int*   degcnt = (int*)alloc((size_t)N * 4);
    float* dinv   = (float*)alloc((size_t)N * 4);
    int*   rowptr = (int*)alloc((size_t)(N + 1) * 4);
    int*   bsum   = (int*)alloc((size_t)128 * 4);
    int*   col    = (int*)alloc((size_t)Emax * 4);
    float* val    = (float*)alloc((size_t)Emax * 4);
    int*   epos   = (int*)alloc((size_t)E * 4);
    uint2* xh     = (uint2*)alloc((size_t)N * 32 * 2);      // x fp16
    uint2* aggXh  = (uint2*)alloc((size_t)N * 32 * 2);      // (A x) fp16
    uint2* bufB   = (uint2*)alloc((size_t)N * HIDDEN * 2);  // h fp16
    uint2* bufH   = (uint2*)alloc((size_t)N * HIDDEN * 2);  // xw fp16
    float* gbuf   = (float*)alloc((size_t)G * HIDDEN * 4);
    (void)ws_size;

    int gN   = (N + 255) / 256;
    int gE   = (E + 255) / 256;
    int gEm  = (Emax + 255) / 256;
    int gGM  = (N + 63) / 64;                               // mfma gemm blocks
    int gAgg32 = (int)(((long long)N * 8 + 255) / 256);
    int gAgg96 = (int)(((long long)N * 24 + 255) / 256);
    int nb   = (N + 1023) / 1024;   // 98 scan blocks (<= 128)

    // ---- CSR build (once per call) ----
    zero_int_kernel<<<gN, 256, 0, stream>>>(degcnt, N);
    zero_int_kernel<<<gEm, 256, 0, stream>>>(col, Emax);
    zero_kernel<<<gEm, 256, 0, stream>>>(val, Emax);
    deg_pos_kernel<<<gE, 256, 0, stream>>>(dst, degcnt, epos, E);
    dinv_kernel<<<gN, 256, 0, stream>>>(degcnt, dinv, N);
    scan_reduce_kernel<<<nb, 256, 0, stream>>>(degcnt, bsum, N);
    scan_bsum_kernel<<<1, 128, 0, stream>>>(bsum, nb);
    scan_write_kernel<<<nb, 256, 0, stream>>>(degcnt, bsum, rowptr, N);
    fill_csr_kernel<<<gE, 256, 0, stream>>>(src, dst, epos, dinv, rowptr, col, val, E);

    // ---- layer 1 reassociated: aggX = A x (32 feats), h1 = aggX W1 + b1 ----
    cast_h_kernel<<<(N * 8 + 255) / 256, 256, 0, stream>>>(
        reinterpret_cast<const float4*>(x), xh, N * 8);
    aggregate_kernel<8, false, false><<<gAgg32, 256, 0, stream>>>(
        xh, rowptr, col, val, dinv, nullptr, aggXh, nullptr, nullptr, N);
    gemm_mfma_kernel<32, false, true><<<gGM, 256, 0, stream>>>(
        reinterpret_cast<const _Float16*>(aggXh), W1, b1,
        reinterpret_cast<_Float16*>(bufB), N);

    // ---- layers 2-3: xw = relu(h) W (fp16, MFMA); h' = A xw + b (fp16) ----
    gemm_mfma_kernel<96, true, false><<<gGM, 256, 0, stream>>>(
        reinterpret_cast<const _Float16*>(bufB), W2, nullptr,
        reinterpret_cast<_Float16*>(bufH), N);
    aggregate_kernel<24, false, true><<<gAgg96, 256, 0, stream>>>(
        bufH, rowptr, col, val, dinv, b2, bufB, nullptr, nullptr, N);

    gemm_mfma_kernel<96, true, false><<<gGM, 256, 0, stream>>>(
        reinterpret_cast<const _Float16*>(bufB), W3, nullptr,
        reinterpret_cast<_Float16*>(bufH), N);
    aggregate_kernel<24, false, true><<<gAgg96, 256, 0, stream>>>(
        bufH, rowptr, col, val, dinv, b3, bufB, nullptr, nullptr, N);

    // ---- layer 4: aggregate fused with relu + global_add_pool (fp32) ----
    zero_kernel<<<(G * HIDDEN + 255) / 256, 256, 0, stream>>>(gbuf, G * HIDDEN);
    gemm_mfma_kernel<96, true, false><<<gGM, 256, 0, stream>>>(
        reinterpret_cast<const _Float16*>(bufB), W4, nullptr,
        reinterpret_cast<_Float16*>(bufH), N);
    aggregate_kernel<24, true, true><<<gAgg96, 256, 0, stream>>>(
        bufH, rowptr, col, val, dinv, b4, nullptr, batch, gbuf, N);

    // ---- MLP head ----
    mlp_kernel<<<G, 64, 0, stream>>>(gbuf, Wf1, bf1, Wf2, bf2, out, G);
}

// Round 12
// 666.696 us; speedup vs baseline: 1.0544x; 1.0544x over previous
//
#include <hip/hip_runtime.h>
#include <hip/hip_fp16.h>

// GCN: 4x GCNConv(relu) -> global_add_pool -> MLP(96->32 relu ->1)
// N=100000 nodes, E=1600000 edges, F=32, H=96, G=2048 graphs.
//
// R12: R10 aggregate (TPN=24 x uint2 fp16, pad4 rows, 4-way unroll, plain
// loads/stores — NT hints reverted: they inflated FETCH +26MB w/ no time win)
// + R11 MFMA GEMMs (v_mfma_f32_16x16x32_f16, W^T in LDS, +8 padded stride).
// Aggregate is at its measured floor: ~3 cyc per divergent 8B lane-request,
// invariant across 9 structural variants (R3-R11).

#define HIDDEN 96

typedef __attribute__((ext_vector_type(8))) _Float16 half8;
typedef __attribute__((ext_vector_type(4))) float floatx4;

__device__ inline float4 h4_to_f4(uint2 u) {
    __half2 a = *reinterpret_cast<__half2*>(&u.x);
    __half2 b = *reinterpret_cast<__half2*>(&u.y);
    float2 fa = __half22float2(a), fb = __half22float2(b);
    return make_float4(fa.x, fa.y, fb.x, fb.y);
}

__device__ inline uint2 f4_to_h4(float4 v) {
    __half2 a = __float22half2_rn(make_float2(v.x, v.y));
    __half2 b = __float22half2_rn(make_float2(v.z, v.w));
    uint2 u;
    u.x = *reinterpret_cast<unsigned*>(&a);
    u.y = *reinterpret_cast<unsigned*>(&b);
    return u;
}

__device__ inline int pad4i(int c) { return (c + 3) & ~3; }

__global__ __launch_bounds__(256) void zero_int_kernel(int* p, int n) {
    int i = blockIdx.x * 256 + threadIdx.x;
    if (i < n) p[i] = 0;
}

__global__ __launch_bounds__(256) void zero_kernel(float* p, int n) {
    int i = blockIdx.x * 256 + threadIdx.x;
    if (i < n) p[i] = 0.0f;
}

__global__ __launch_bounds__(256) void cast_h_kernel(const float4* __restrict__ in,
                                                     uint2* __restrict__ out, int n4) {
    int i = blockIdx.x * 256 + threadIdx.x;
    if (i < n4) out[i] = f4_to_h4(in[i]);
}

// in-degree histogram over dst; epos[e] = this edge's slot within its dst row
__global__ __launch_bounds__(256) void deg_pos_kernel(const int* __restrict__ dst,
                                                      int* __restrict__ cnt,
                                                      int* __restrict__ epos, int E) {
    int e = blockIdx.x * 256 + threadIdx.x;
    if (e < E) epos[e] = atomicAdd(&cnt[dst[e]], 1);
}

__global__ __launch_bounds__(256) void dinv_kernel(const int* __restrict__ cnt,
                                                   float* __restrict__ dinv, int n) {
    int i = blockIdx.x * 256 + threadIdx.x;
    if (i < n) dinv[i] = rsqrtf((float)(cnt[i] + 1));
}

// ---- 3-phase multi-block exclusive scan of pad4(cnt[0..N)) -> rowptr ----
__global__ __launch_bounds__(256) void scan_reduce_kernel(const int* __restrict__ cnt,
                                                          int* __restrict__ bsum, int N) {
    __shared__ int s[256];
    int b = blockIdx.x, tid = threadIdx.x;
    int base = b * 1024;
    int v = 0;
    for (int j = tid; j < 1024; j += 256) {
        int i = base + j;
        v += (i < N) ? pad4i(cnt[i]) : 0;
    }
    s[tid] = v;
    __syncthreads();
    for (int off = 128; off > 0; off >>= 1) {
        if (tid < off) s[tid] += s[tid + off];
        __syncthreads();
    }
    if (tid == 0) bsum[b] = s[0];
}

__global__ __launch_bounds__(128) void scan_bsum_kernel(int* __restrict__ bsum, int nb) {
    __shared__ int s[128];
    int tid = threadIdx.x;
    int v = (tid < nb) ? bsum[tid] : 0;
    s[tid] = v;
    __syncthreads();
    for (int off = 1; off < 128; off <<= 1) {
        int t = (tid >= off) ? s[tid - off] : 0;
        __syncthreads();
        s[tid] += t;
        __syncthreads();
    }
    if (tid < nb) bsum[tid] = s[tid] - v;  // exclusive
}

__global__ __launch_bounds__(256) void scan_write_kernel(const int* __restrict__ cnt,
                                                         const int* __restrict__ bsum,
                                                         int* __restrict__ rowptr, int N) {
    __shared__ int ts[256];
    int b = blockIdx.x, tid = threadIdx.x;
    int base = b * 1024 + tid * 4;
    int v0 = (base + 0 < N) ? pad4i(cnt[base + 0]) : 0;
    int v1 = (base + 1 < N) ? pad4i(cnt[base + 1]) : 0;
    int v2 = (base + 2 < N) ? pad4i(cnt[base + 2]) : 0;
    int v3 = (base + 3 < N) ? pad4i(cnt[base + 3]) : 0;
    int sum = v0 + v1 + v2 + v3;
    ts[tid] = sum;
    __syncthreads();
    for (int off = 1; off < 256; off <<= 1) {
        int t = (tid >= off) ? ts[tid - off] : 0;
        __syncthreads();
        ts[tid] += t;
        __syncthreads();
    }
    int excl = bsum[b] + ts[tid] - sum;
    if (base + 0 <= N) rowptr[base + 0] = excl;
    if (base + 1 <= N) rowptr[base + 1] = excl + v0;
    if (base + 2 <= N) rowptr[base + 2] = excl + v0 + v1;
    if (base + 3 <= N) rowptr[base + 3] = excl + v0 + v1 + v2;
}

// Fill CSR slots (no atomics). Padding slots stay col=0,val=0 (pre-zeroed).
__global__ __launch_bounds__(256) void fill_csr_kernel(const int* __restrict__ src,
                                                       const int* __restrict__ dst,
                                                       const int* __restrict__ epos,
                                                       const float* __restrict__ dinv,
                                                       const int* __restrict__ rowptr,
                                                       int* __restrict__ col,
                                                       float* __restrict__ val, int E) {
    int e = blockIdx.x * 256 + threadIdx.x;
    if (e >= E) return;
    int s = src[e];
    int d = dst[e];
    int idx = rowptr[d] + epos[e];
    col[idx] = s;
    val[idx] = dinv[s] * dinv[d];
}

// MFMA GEMM: Y[n x 96] (fp16) = act(X[n x K] fp16) @ W[K x 96] (+ b).
// v_mfma_f32_16x16x32_f16. Block = 4 waves; wave computes 16 rows x 96 cols.
// W staged transposed in LDS (stride K+8 halfs). C/D: col=lane&15,
// row=quad*4+reg (guide-verified, dtype-independent).
template <int K, bool RELU, bool BIAS>
__global__ __launch_bounds__(256) void gemm_mfma_kernel(const _Float16* __restrict__ X,
                                                        const float* __restrict__ W,
                                                        const float* __restrict__ b,
                                                        _Float16* __restrict__ Y, int n) {
    constexpr int KS = K + 8;
    __shared__ _Float16 blds[96 * KS];
    int tid = threadIdx.x;
    for (int idx = tid; idx < 96 * K; idx += 256) {
        int nn = idx / K, kk = idx - nn * K;
        blds[nn * KS + kk] = (_Float16)W[kk * 96 + nn];
    }
    __syncthreads();

    int wave = tid >> 6, lane = tid & 63;
    int m = lane & 15, quad = lane >> 4;
    int row0 = blockIdx.x * 64 + wave * 16;
    int rowA = row0 + m;
    int rowc = (rowA < n) ? rowA : (n - 1);

    floatx4 acc[6];
#pragma unroll
    for (int t = 0; t < 6; t++) acc[t] = (floatx4){0.f, 0.f, 0.f, 0.f};

    const _Float16* xrow = X + (size_t)rowc * K;
#pragma unroll
    for (int k0 = 0; k0 < K; k0 += 32) {
        half8 a = *reinterpret_cast<const half8*>(xrow + k0 + quad * 8);
        if (RELU) {
#pragma unroll
            for (int j = 0; j < 8; j++) a[j] = (a[j] > (_Float16)0) ? a[j] : (_Float16)0;
        }
#pragma unroll
        for (int t = 0; t < 6; t++) {
            half8 bf = *reinterpret_cast<const half8*>(
                blds + (t * 16 + m) * KS + k0 + quad * 8);
            acc[t] = __builtin_amdgcn_mfma_f32_16x16x32_f16(a, bf, acc[t], 0, 0, 0);
        }
    }

#pragma unroll
    for (int t = 0; t < 6; t++) {
        float bb = BIAS ? b[t * 16 + m] : 0.f;
#pragma unroll
        for (int r = 0; r < 4; r++) {
            int rowO = row0 + quad * 4 + r;
            if (rowO < n) Y[(size_t)rowO * 96 + t * 16 + m] = (_Float16)(acc[t][r] + bb);
        }
    }
}

// out[i] = dinv[i]^2*xw[i] (+ b) + sum_e val[e]*xw[col[e]], xw fp16.
// TPN threads/node (uint2 8B lanes), pad4 rows, 4-way unroll, plain loads.
// fp32 accumulate. POOL: atomicAdd relu into gpool[batch[i]].
template <int TPN, bool POOL, bool BIAS>
__global__ __launch_bounds__(256) void aggregate_kernel(const uint2* __restrict__ xwh,
                                                        const int* __restrict__ rowptr,
                                                        const int* __restrict__ col,
                                                        const float* __restrict__ val,
                                                        const float* __restrict__ dinv,
                                                        const float* __restrict__ b,
                                                        uint2* __restrict__ out,
                                                        const int* __restrict__ batch,
                                                        float* __restrict__ gpool, int n) {
    unsigned t = blockIdx.x * 256 + threadIdx.x;
    unsigned i = t / (unsigned)TPN, q = t % (unsigned)TPN;
    if (i >= (unsigned)n) return;

    float dv = dinv[i];
    float s = dv * dv;
    float4 self = h4_to_f4(xwh[i * TPN + q]);
    float4 acc = make_float4(s * self.x, s * self.y, s * self.z, s * self.w);
    if (BIAS) {
        float4 bb = reinterpret_cast<const float4*>(b)[q];
        acc.x += bb.x; acc.y += bb.y; acc.z += bb.z; acc.w += bb.w;
    }

    int e = rowptr[i], end = rowptr[i + 1];
    for (; e < end; e += 4) {
        int4 c4 = *reinterpret_cast<const int4*>(col + e);
        float4 w4 = *reinterpret_cast<const float4*>(val + e);
        uint2 u0 = xwh[(unsigned)c4.x * TPN + q];
        uint2 u1 = xwh[(unsigned)c4.y * TPN + q];
        uint2 u2 = xwh[(unsigned)c4.z * TPN + q];
        uint2 u3 = xwh[(unsigned)c4.w * TPN + q];
        float4 v0 = h4_to_f4(u0), v1 = h4_to_f4(u1);
        float4 v2 = h4_to_f4(u2), v3 = h4_to_f4(u3);
        acc.x += w4.x * v0.x + w4.y * v1.x + w4.z * v2.x + w4.w * v3.x;
        acc.y += w4.x * v0.y + w4.y * v1.y + w4.z * v2.y + w4.w * v3.y;
        acc.z += w4.x * v0.z + w4.y * v1.z + w4.z * v2.z + w4.w * v3.z;
        acc.w += w4.x * v0.w + w4.y * v1.w + w4.z * v2.w + w4.w * v3.w;
    }

    if (POOL) {
        float* o = gpool + (size_t)batch[i] * (TPN * 4);
        unsigned fo = q * 4u;
        atomicAdd(o + fo + 0, fmaxf(acc.x, 0.f));
        atomicAdd(o + fo + 1, fmaxf(acc.y, 0.f));
        atomicAdd(o + fo + 2, fmaxf(acc.z, 0.f));
        atomicAdd(o + fo + 3, fmaxf(acc.w, 0.f));
    } else {
        out[i * TPN + q] = f4_to_h4(acc);
    }
}

__global__ __launch_bounds__(64) void mlp_kernel(const float* __restrict__ g,
                                                 const float* __restrict__ Wf1,
                                                 const float* __restrict__ bf1,
                                                 const float* __restrict__ Wf2,
                                                 const float* __restrict__ bf2,
                                                 float* __restrict__ out, int G) {
    __shared__ float gs[HIDDEN];
    __shared__ float hid[32];
    int blk = blockIdx.x;
    int lane = threadIdx.x;
    for (int idx = lane; idx < HIDDEN; idx += 64) gs[idx] = g[(size_t)blk * HIDDEN + idx];
    __syncthreads();
    if (lane < 32) {
        float a = bf1[lane];
        for (int k = 0; k < HIDDEN; k++) a = fmaf(gs[k], Wf1[k * 32 + lane], a);
        hid[lane] = fmaxf(a, 0.f);
    }
    __syncthreads();
    if (lane == 0) {
        float o = bf2[0];
        for (int k = 0; k < 32; k++) o = fmaf(hid[k], Wf2[k], o);
        out[blk] = o;
    }
}

extern "C" void kernel_launch(void* const* d_in, const int* in_sizes, int n_in,
                              void* d_out, int out_size, void* d_ws, size_t ws_size,
                              hipStream_t stream) {
    const float* x     = (const float*)d_in[0];
    const int*   ei    = (const int*)d_in[1];
    const int*   batch = (const int*)d_in[2];
    const float* W1 = (const float*)d_in[3];  const float* b1 = (const float*)d_in[4];
    const float* W2 = (const float*)d_in[5];  const float* b2 = (const float*)d_in[6];
    const float* W3 = (const float*)d_in[7];  const float* b3 = (const float*)d_in[8];
    const float* W4 = (const float*)d_in[9];  const float* b4 = (const float*)d_in[10];
    const float* Wf1 = (const float*)d_in[11]; const float* bf1 = (const float*)d_in[12];
    const float* Wf2 = (const float*)d_in[13]; const float* bf2 = (const float*)d_in[14];
    float* out = (float*)d_out;

    int N = in_sizes[0] / 32;   // 100000
    int E = in_sizes[1] / 2;    // 1600000
    int G = out_size;           // 2048
    const int* src = ei;
    const int* dst = ei + E;
    int Emax = E + 4 * N;       // pad4-CSR upper bound (2.0M)

    // Workspace layout (~72 MB)
    char* ws = (char*)d_ws;
    size_t off = 0;
    auto alloc = [&](size_t bytes) -> void* {
        void* p = (void*)(ws + off);
        off += (bytes + 255) & ~(size_t)255;
        return p;
    };
    int*   degcnt = (int*)alloc((size_t)N * 4);
    float* dinv   = (float*)alloc((size_t)N * 4);
    int*   rowptr = (int*)alloc((size_t)(N + 1) * 4);
    int*   bsum   = (int*)alloc((size_t)128 * 4);
    int*   col    = (int*)alloc((size_t)Emax * 4);
    float* val    = (float*)alloc((size_t)Emax * 4);
    int*   epos   = (int*)alloc((size_t)E * 4);
    uint2* xh     = (uint2*)alloc((size_t)N * 32 * 2);      // x fp16
    uint2* aggXh  = (uint2*)alloc((size_t)N * 32 * 2);      // (A x) fp16
    uint2* bufB   = (uint2*)alloc((size_t)N * HIDDEN * 2);  // h fp16
    uint2* bufH   = (uint2*)alloc((size_t)N * HIDDEN * 2);  // xw fp16
    float* gbuf   = (float*)alloc((size_t)G * HIDDEN * 4);
    (void)ws_size;

    int gN   = (N + 255) / 256;
    int gE   = (E + 255) / 256;
    int gEm  = (Emax + 255) / 256;
    int gGM  = (N + 63) / 64;                               // mfma gemm blocks
    int gAgg32 = (int)(((long long)N * 8 + 255) / 256);
    int gAgg96 = (int)(((long long)N * 24 + 255) / 256);
    int nb   = (N + 1023) / 1024;   // 98 scan blocks (<= 128)

    // ---- CSR build (once per call) ----
    zero_int_kernel<<<gN, 256, 0, stream>>>(degcnt, N);
    zero_int_kernel<<<gEm, 256, 0, stream>>>(col, Emax);
    zero_kernel<<<gEm, 256, 0, stream>>>(val, Emax);
    deg_pos_kernel<<<gE, 256, 0, stream>>>(dst, degcnt, epos, E);
    dinv_kernel<<<gN, 256, 0, stream>>>(degcnt, dinv, N);
    scan_reduce_kernel<<<nb, 256, 0, stream>>>(degcnt, bsum, N);
    scan_bsum_kernel<<<1, 128, 0, stream>>>(bsum, nb);
    scan_write_kernel<<<nb, 256, 0, stream>>>(degcnt, bsum, rowptr, N);
    fill_csr_kernel<<<gE, 256, 0, stream>>>(src, dst, epos, dinv, rowptr, col, val, E);

    // ---- layer 1 reassociated: aggX = A x (32 feats), h1 = aggX W1 + b1 ----
    cast_h_kernel<<<(N * 8 + 255) / 256, 256, 0, stream>>>(
        reinterpret_cast<const float4*>(x), xh, N * 8);
    aggregate_kernel<8, false, false><<<gAgg32, 256, 0, stream>>>(
        xh, rowptr, col, val, dinv, nullptr, aggXh, nullptr, nullptr, N);
    gemm_mfma_kernel<32, false, true><<<gGM, 256, 0, stream>>>(
        reinterpret_cast<const _Float16*>(aggXh), W1, b1,
        reinterpret_cast<_Float16*>(bufB), N);

    // ---- layers 2-3: xw = relu(h) W (fp16, MFMA); h' = A xw + b (fp16) ----
    gemm_mfma_kernel<96, true, false><<<gGM, 256, 0, stream>>>(
        reinterpret_cast<const _Float16*>(bufB), W2, nullptr,
        reinterpret_cast<_Float16*>(bufH), N);
    aggregate_kernel<24, false, true><<<gAgg96, 256, 0, stream>>>(
        bufH, rowptr, col, val, dinv, b2, bufB, nullptr, nullptr, N);

    gemm_mfma_kernel<96, true, false><<<gGM, 256, 0, stream>>>(
        reinterpret_cast<const _Float16*>(bufB), W3, nullptr,
        reinterpret_cast<_Float16*>(bufH), N);
    aggregate_kernel<24, false, true><<<gAgg96, 256, 0, stream>>>(
        bufH, rowptr, col, val, dinv, b3, bufB, nullptr, nullptr, N);

    // ---- layer 4: aggregate fused with relu + global_add_pool (fp32) ----
    zero_kernel<<<(G * HIDDEN + 255) / 256, 256, 0, stream>>>(gbuf, G * HIDDEN);
    gemm_mfma_kernel<96, true, false><<<gGM, 256, 0, stream>>>(
        reinterpret_cast<const _Float16*>(bufB), W4, nullptr,
        reinterpret_cast<_Float16*>(bufH), N);
    aggregate_kernel<24, true, true><<<gAgg96, 256, 0, stream>>>(
        bufH, rowptr, col, val, dinv, b4, nullptr, batch, gbuf, N);

    // ---- MLP head ----
    mlp_kernel<<<G, 64, 0, stream>>>(gbuf, Wf1, bf1, Wf2, bf2, out, G);
}